// Round 4
// baseline (848.351 us; speedup 1.0000x reference)
//
#include <hip/hip_runtime.h>

// ---------- types / helpers ----------
typedef _Float16 h8 __attribute__((ext_vector_type(8)));
typedef float f32x4 __attribute__((ext_vector_type(4)));

__device__ __forceinline__ float clampf(float x, float lo, float hi) {
    return fminf(fmaxf(x, lo), hi);   // NaN -> lo
}
__device__ __forceinline__ unsigned short f2bf(float f) {
    unsigned int v;
    __builtin_memcpy(&v, &f, 4);
    v += 0x7FFFu + ((v >> 16) & 1u);   // round-to-nearest-even
    return (unsigned short)(v >> 16);
}
__device__ __forceinline__ float bf2f(unsigned short u) {
    unsigned int v = ((unsigned int)u) << 16;
    float f;
    __builtin_memcpy(&f, &v, 4);
    return f;
}

// ---------- transpose f32 -> f16 (out[c][r] = in[r][c]) ----------
__global__ __launch_bounds__(256) void transpose_f2h(const float* __restrict__ in,
                                                     _Float16* __restrict__ out,
                                                     int rows, int cols) {
    __shared__ _Float16 tile[32][33];
    int bx = blockIdx.x * 32, by = blockIdx.y * 32;
    int tx = threadIdx.x & 31, ty = threadIdx.x >> 5;
    for (int i = ty; i < 32; i += 8)
        tile[i][tx] = (_Float16)in[(size_t)(by + i) * cols + bx + tx];
    __syncthreads();
    for (int i = ty; i < 32; i += 8)
        out[(size_t)(bx + i) * rows + by + tx] = tile[tx][i];
}

// ---------- LN1: f32 x -> f16 normed (one wave per 512-ch row) ----------
__global__ __launch_bounds__(256) void ln1_kernel(const float* __restrict__ x,
                                                  const float* __restrict__ scale,
                                                  _Float16* __restrict__ out) {
    int row = blockIdx.x * 4 + (threadIdx.x >> 6);
    int lane = threadIdx.x & 63;
    const float4* xp = (const float4*)(x + (size_t)row * 512 + lane * 8);
    float4 a = xp[0], b = xp[1];
    const float4* sp = (const float4*)(scale + lane * 8);
    float4 s0v = sp[0], s1v = sp[1];
    float f[8] = {a.x, a.y, a.z, a.w, b.x, b.y, b.z, b.w};
    float sc[8] = {s0v.x, s0v.y, s0v.z, s0v.w, s1v.x, s1v.y, s1v.z, s1v.w};
    float s = 0.f, ss = 0.f;
#pragma unroll
    for (int j = 0; j < 8; j++) { s += f[j]; ss += f[j] * f[j]; }
#pragma unroll
    for (int off = 1; off < 64; off <<= 1) { s += __shfl_xor(s, off); ss += __shfl_xor(ss, off); }
    float mean = s * (1.f / 512.f);
    float var  = ss * (1.f / 512.f) - mean * mean;
    float rs   = rsqrtf(fmaxf(var, 0.f) + 1e-5f);
    union { uint4 u; _Float16 h[8]; } ov;
#pragma unroll
    for (int j = 0; j < 8; j++) ov.h[j] = (_Float16)((f[j] - mean) * rs * sc[j]);
    *(uint4*)(out + (size_t)row * 512 + lane * 8) = ov.u;
}

// ---------- GEMM C[M][:] = A[M][K] * BT[N][K]^T, f16 in, fp32 acc ----------
__global__ __launch_bounds__(256) void gemm_bt(const _Float16* __restrict__ A,
                                               const _Float16* __restrict__ BT,
                                               _Float16* __restrict__ Cf16,
                                               unsigned short* __restrict__ Cbf16,
                                               const float* __restrict__ bias,
                                               int K, int ldc, float outscale) {
    __shared__ __attribute__((aligned(16))) _Float16 As[64][40];
    __shared__ __attribute__((aligned(16))) _Float16 Bs[64][40];
    int t = threadIdx.x;
    int wave = t >> 6, lane = t & 63;
    int lm = lane & 15, q4 = lane >> 4;
    int m0 = blockIdx.y * 64, n0 = blockIdx.x * 64;
    f32x4 acc[4];
#pragma unroll
    for (int i = 0; i < 4; i++) acc[i] = (f32x4){0.f, 0.f, 0.f, 0.f};

    int sr = t >> 2, sc = (t & 3) * 8;
    const _Float16* Ag = A + (size_t)(m0 + sr) * K + sc;
    const _Float16* Bg = BT + (size_t)(n0 + sr) * K + sc;

    for (int k0 = 0; k0 < K; k0 += 32) {
        *(uint4*)(&As[sr][sc]) = *(const uint4*)(Ag + k0);
        *(uint4*)(&Bs[sr][sc]) = *(const uint4*)(Bg + k0);
        __syncthreads();
        h8 af = *(const h8*)(&As[wave * 16 + lm][q4 * 8]);
#pragma unroll
        for (int nt = 0; nt < 4; nt++) {
            h8 bf = *(const h8*)(&Bs[nt * 16 + lm][q4 * 8]);
            acc[nt] = __builtin_amdgcn_mfma_f32_16x16x32_f16(af, bf, acc[nt], 0, 0, 0);
        }
        __syncthreads();
    }
#pragma unroll
    for (int nt = 0; nt < 4; nt++) {
        int col = n0 + nt * 16 + lm;
        float bv = bias ? bias[col] : 0.f;
#pragma unroll
        for (int r = 0; r < 4; r++) {
            int row = m0 + wave * 16 + q4 * 4 + r;
            float v = acc[nt][r] * outscale + bv;
            if (Cf16) Cf16[(size_t)row * ldc + col] = (_Float16)v;
            else      Cbf16[(size_t)row * ldc + col] = f2bf(v);
        }
    }
}

// ---------- context (per chunk): ctx[d][e] = sum_n softmax_n(k)[n,d] * v[n,e]  (x1024) ----------
// kv chunk layout: [nb*1024][1024] f16, k_h at col h*64, v_h at col 512+h*64; b is chunk-local
__global__ __launch_bounds__(256) void context_kernel(const _Float16* __restrict__ kv,
                                                      float* __restrict__ ctx) {
    int b = blockIdx.x >> 3, h = blockIdx.x & 7;
    __shared__ __attribute__((aligned(16))) _Float16 ks[16][64];
    __shared__ __attribute__((aligned(16))) _Float16 vs[16][64];
    int t = threadIdx.x;
    int d = t >> 2, eg = t & 3;
    int lrow = t >> 4, lseg = t & 15;
    float acc[16];
#pragma unroll
    for (int j = 0; j < 16; j++) acc[j] = 0.f;
    float S = 0.f;

    for (int n0 = 0; n0 < 1024; n0 += 16) {
        __syncthreads();
        const _Float16* src = kv + ((size_t)b * 1024 + n0 + lrow) * 1024 + h * 64 +
                              (lseg < 8 ? lseg * 8 : 512 + (lseg - 8) * 8);
        uint4 val = *(const uint4*)src;
        if (lseg < 8) *(uint4*)(&ks[lrow][lseg * 8]) = val;
        else          *(uint4*)(&vs[lrow][(lseg - 8) * 8]) = val;
        __syncthreads();
#pragma unroll 4
        for (int nn = 0; nn < 16; nn++) {
            float ek = __expf(clampf((float)ks[nn][d], -30.f, 30.f));
            S += ek;
            union { uint4 u; _Float16 hh[8]; } v0, v1;
            v0.u = *(const uint4*)(&vs[nn][eg * 16]);
            v1.u = *(const uint4*)(&vs[nn][eg * 16 + 8]);
#pragma unroll
            for (int j = 0; j < 8; j++) acc[j] += ek * (float)v0.hh[j];
#pragma unroll
            for (int j = 0; j < 8; j++) acc[8 + j] += ek * (float)v1.hh[j];
        }
    }
    float inv = 1.f / S;   // 1/N folded into GEMM2 outscale
    float* dst = ctx + (((size_t)(b * 8 + h)) * 64 + d) * 64 + eg * 16;
#pragma unroll
    for (int g = 0; g < 4; g++) {
        union { float4 f4; float f[4]; } w;
#pragma unroll
        for (int j = 0; j < 4; j++) w.f[j] = acc[g * 4 + j] * inv;
        *(float4*)(dst + g * 4) = w.f4;
    }
}

// ---------- fused q-softmax + PV (per chunk): attn[n][h*64+e] = sum_d (softmax_d(q)/8)[d]*ctx[d][e] ----------
__global__ __launch_bounds__(256) void attnout_kernel(const _Float16* __restrict__ qbuf,
                                                      const float* __restrict__ ctx,
                                                      _Float16* __restrict__ attn) {
    int bid = blockIdx.x;
    int nc = bid & 15, h = (bid >> 4) & 7, b = bid >> 7;   // b chunk-local
    __shared__ float cs[64][64];
    int t = threadIdx.x, wave = t >> 6, lane = t & 63;
    const float4* src = (const float4*)(ctx + (size_t)(b * 8 + h) * 4096);
    float4* csf = (float4*)(&cs[0][0]);
    for (int i = t; i < 1024; i += 256) csf[i] = src[i];
    __syncthreads();
    for (int r = 0; r < 16; r++) {
        int n = nc * 64 + r * 4 + wave;
        size_t p = ((size_t)b * 1024 + n) * 512 + h * 64;
        float qe = __expf(clampf((float)qbuf[p + lane], -30.f, 30.f));
        float ssum = qe;
#pragma unroll
        for (int off = 1; off < 64; off <<= 1) ssum += __shfl_xor(ssum, off);
        float qn = qe / (ssum * 8.f);          // softmax / sqrt(64)
        float o = 0.f;
        for (int d = 0; d < 64; d++) o += __shfl(qn, d) * cs[d][lane];
        attn[((size_t)b * 1024 + n) * 512 + h * 64 + lane] = (_Float16)o;
    }
}

// ---------- LN2 + residual: out = LN(proj)*scale + x  (proj bf16, x/out f32) ----------
__global__ __launch_bounds__(256) void ln2_res_kernel(const unsigned short* __restrict__ proj,
                                                      const float* __restrict__ x,
                                                      const float* __restrict__ scale,
                                                      float* __restrict__ out) {
    int row = blockIdx.x * 4 + (threadIdx.x >> 6);
    int lane = threadIdx.x & 63;
    size_t off = (size_t)row * 512 + lane * 8;
    union { uint4 u; unsigned short us[8]; } pv;
    pv.u = *(const uint4*)(proj + off);
    const float4* xp = (const float4*)(x + off);
    float4 xa = xp[0], xb = xp[1];
    const float4* sp = (const float4*)(scale + lane * 8);
    float4 s0v = sp[0], s1v = sp[1];
    float xr[8] = {xa.x, xa.y, xa.z, xa.w, xb.x, xb.y, xb.z, xb.w};
    float sc[8] = {s0v.x, s0v.y, s0v.z, s0v.w, s1v.x, s1v.y, s1v.z, s1v.w};
    float f[8], s = 0.f, ss = 0.f;
#pragma unroll
    for (int j = 0; j < 8; j++) { f[j] = bf2f(pv.us[j]); s += f[j]; ss += f[j] * f[j]; }
#pragma unroll
    for (int o2 = 1; o2 < 64; o2 <<= 1) { s += __shfl_xor(s, o2); ss += __shfl_xor(ss, o2); }
    float mean = s * (1.f / 512.f);
    float var  = ss * (1.f / 512.f) - mean * mean;
    float rs   = rsqrtf(fmaxf(var, 0.f) + 1e-5f);
    float4 o0, o1;
    float* o0p = &o0.x; float* o1p = &o1.x;
#pragma unroll
    for (int j = 0; j < 4; j++) o0p[j] = (f[j] - mean) * rs * sc[j] + xr[j];
#pragma unroll
    for (int j = 0; j < 4; j++) o1p[j] = (f[4 + j] - mean) * rs * sc[4 + j] + xr[4 + j];
    float4* op = (float4*)(out + off);
    op[0] = o0; op[1] = o1;
}

// ---------- launch ----------
extern "C" void kernel_launch(void* const* d_in, const int* in_sizes, int n_in,
                              void* d_out, int out_size, void* d_ws, size_t ws_size,
                              hipStream_t stream) {
    const float* x    = (const float*)d_in[0];
    const float* ln1s = (const float*)d_in[1];
    const float* wqkv = (const float*)d_in[2];
    const float* wout = (const float*)d_in[3];
    const float* bout = (const float*)d_in[4];
    const float* ln2s = (const float*)d_in[5];
    float* out = (float*)d_out;

    char* ws = (char*)d_ws;
    // ws (38 MB): wqkvT f16 [1536][512] | woutT f16 [512][512] | ctx f32 [256][64][64] | normed f16 [32768][512]
    _Float16* wqkvT  = (_Float16*)(ws);
    _Float16* woutT  = (_Float16*)(ws + 1572864);
    float*    ctx    = (float*)(ws + 2097152);
    _Float16* normed = (_Float16*)(ws + 6291456);
    unsigned short* proj = (unsigned short*)(ws + 6291456);  // reuses dead normed slot (bf16)
    // d_out (67 MB f32) doubles as scratch: attn f16 [32768][512] in first half,
    // kv/q chunk f16 [16*1024][1024] in second half. Both dead before ln2 writes out.
    _Float16* attnF = (_Float16*)d_out;
    _Float16* kvbuf = (_Float16*)((char*)d_out + 33554432);

    const int nb = 16, nchunks = 2;

    transpose_f2h<<<dim3(48, 16), 256, 0, stream>>>(wqkv, wqkvT, 512, 1536);
    transpose_f2h<<<dim3(16, 16), 256, 0, stream>>>(wout, woutT, 512, 512);
    ln1_kernel<<<8192, 256, 0, stream>>>(x, ln1s, normed);

    for (int c = 0; c < nchunks; c++) {
        size_t row0 = (size_t)c * nb * 1024;
        const _Float16* normed_c = normed + row0 * 512;
        float* ctx_c = ctx + (size_t)c * nb * 8 * 4096;
        // kv = normed_c . w_qkv[:, 512:1536]
        gemm_bt<<<dim3(16, nb * 16), 256, 0, stream>>>(normed_c, wqkvT + 512 * 512,
                                                       kvbuf, nullptr, nullptr, 512, 1024, 1.f);
        context_kernel<<<nb * 8, 256, 0, stream>>>(kvbuf, ctx_c);
        // q = normed_c . w_qkv[:, 0:512]  (overwrites dead kv chunk)
        gemm_bt<<<dim3(8, nb * 16), 256, 0, stream>>>(normed_c, wqkvT,
                                                      kvbuf, nullptr, nullptr, 512, 512, 1.f);
        attnout_kernel<<<nb * 128, 256, 0, stream>>>(kvbuf, ctx_c, attnF + row0 * 512);
    }

    // proj = attn . w_out^T * (1/1024) + b_out   (normed dead -> proj slot)
    gemm_bt<<<dim3(8, 512), 256, 0, stream>>>(attnF, woutT, nullptr, proj, bout,
                                              512, 512, 1.f / 1024.f);
    ln2_res_kernel<<<8192, 256, 0, stream>>>(proj, x, ln2s, out);
}

// Round 5
// 806.630 us; speedup vs baseline: 1.0517x; 1.0517x over previous
//
#include <hip/hip_runtime.h>

// ---------- types / helpers ----------
typedef _Float16 h8 __attribute__((ext_vector_type(8)));
typedef _Float16 h4v __attribute__((ext_vector_type(4)));
typedef float f32x4 __attribute__((ext_vector_type(4)));

__device__ __forceinline__ float clampf(float x, float lo, float hi) {
    return fminf(fmaxf(x, lo), hi);
}
__device__ __forceinline__ unsigned short f2bf(float f) {
    unsigned int v;
    __builtin_memcpy(&v, &f, 4);
    v += 0x7FFFu + ((v >> 16) & 1u);
    return (unsigned short)(v >> 16);
}
__device__ __forceinline__ float bf2f(unsigned short u) {
    unsigned int v = ((unsigned int)u) << 16;
    float f;
    __builtin_memcpy(&f, &v, 4);
    return f;
}

// ---------- transpose f32 -> f16 (out[c][r] = in[r][c]) ----------
__global__ __launch_bounds__(256) void transpose_f2h(const float* __restrict__ in,
                                                     _Float16* __restrict__ out,
                                                     int rows, int cols) {
    __shared__ _Float16 tile[32][33];
    int bx = blockIdx.x * 32, by = blockIdx.y * 32;
    int tx = threadIdx.x & 31, ty = threadIdx.x >> 5;
    for (int i = ty; i < 32; i += 8)
        tile[i][tx] = (_Float16)in[(size_t)(by + i) * cols + bx + tx];
    __syncthreads();
    for (int i = ty; i < 32; i += 8)
        out[(size_t)(bx + i) * rows + by + tx] = tile[tx][i];
}

// ---------- LN1: f32 x -> f16 normed (one wave per 512-ch row) ----------
__global__ __launch_bounds__(256) void ln1_kernel(const float* __restrict__ x,
                                                  const float* __restrict__ scale,
                                                  _Float16* __restrict__ out) {
    int row = blockIdx.x * 4 + (threadIdx.x >> 6);
    int lane = threadIdx.x & 63;
    const float4* xp = (const float4*)(x + (size_t)row * 512 + lane * 8);
    float4 a = xp[0], b = xp[1];
    const float4* sp = (const float4*)(scale + lane * 8);
    float4 s0v = sp[0], s1v = sp[1];
    float f[8] = {a.x, a.y, a.z, a.w, b.x, b.y, b.z, b.w};
    float sc[8] = {s0v.x, s0v.y, s0v.z, s0v.w, s1v.x, s1v.y, s1v.z, s1v.w};
    float s = 0.f, ss = 0.f;
#pragma unroll
    for (int j = 0; j < 8; j++) { s += f[j]; ss += f[j] * f[j]; }
#pragma unroll
    for (int off = 1; off < 64; off <<= 1) { s += __shfl_xor(s, off); ss += __shfl_xor(ss, off); }
    float mean = s * (1.f / 512.f);
    float var  = ss * (1.f / 512.f) - mean * mean;
    float rs   = rsqrtf(fmaxf(var, 0.f) + 1e-5f);
    union { uint4 u; _Float16 h[8]; } ov;
#pragma unroll
    for (int j = 0; j < 8; j++) ov.h[j] = (_Float16)((f[j] - mean) * rs * sc[j]);
    *(uint4*)(out + (size_t)row * 512 + lane * 8) = ov.u;
}

// ---------- GEMM 128x128 tile: C[M][:] = A[M][K] * BT[N][K]^T, f16 in, fp32 acc ----------
// 4 waves in 2x2; each wave 64x64 = 4x4 MFMA 16x16x32 tiles.
// mfma(bf, af): within tile, C row <- lane&15, cols <- (lane>>4)*4 + r (4 consecutive -> 8B store)
__global__ __launch_bounds__(256) void gemm128(const _Float16* __restrict__ A,
                                               const _Float16* __restrict__ BT,
                                               _Float16* __restrict__ Cf16,
                                               unsigned short* __restrict__ Cbf16,
                                               const float* __restrict__ bias,
                                               int K, int ldc, float outscale) {
    __shared__ __attribute__((aligned(16))) _Float16 As[128][40];  // +8 pad: kills b128 bank conflicts
    __shared__ __attribute__((aligned(16))) _Float16 Bs[128][40];
    int t = threadIdx.x, w = t >> 6, lane = t & 63;
    int lm = lane & 15, q4 = lane >> 4;
    int m0 = blockIdx.y * 128, n0 = blockIdx.x * 128;
    int wm = (w & 1) * 64, wn = (w >> 1) * 64;
    f32x4 acc[4][4];
#pragma unroll
    for (int i = 0; i < 4; i++)
#pragma unroll
        for (int j = 0; j < 4; j++) acc[i][j] = (f32x4){0.f, 0.f, 0.f, 0.f};

    int sr = t >> 2, sc = (t & 3) * 8;   // sr 0..63, sc {0,8,16,24}
    const _Float16* Ag = A + (size_t)(m0 + sr) * K + sc;
    const _Float16* Bg = BT + (size_t)(n0 + sr) * K + sc;

    for (int k0 = 0; k0 < K; k0 += 32) {
        uint4 a0 = *(const uint4*)(Ag + k0);
        uint4 a1 = *(const uint4*)(Ag + (size_t)64 * K + k0);
        uint4 b0 = *(const uint4*)(Bg + k0);
        uint4 b1 = *(const uint4*)(Bg + (size_t)64 * K + k0);
        __syncthreads();
        *(uint4*)(&As[sr][sc])      = a0;
        *(uint4*)(&As[sr + 64][sc]) = a1;
        *(uint4*)(&Bs[sr][sc])      = b0;
        *(uint4*)(&Bs[sr + 64][sc]) = b1;
        __syncthreads();
        h8 af[4], bf[4];
#pragma unroll
        for (int i = 0; i < 4; i++) af[i] = *(const h8*)(&As[wm + i * 16 + lm][q4 * 8]);
#pragma unroll
        for (int i = 0; i < 4; i++) bf[i] = *(const h8*)(&Bs[wn + i * 16 + lm][q4 * 8]);
#pragma unroll
        for (int mi = 0; mi < 4; mi++)
#pragma unroll
            for (int ni = 0; ni < 4; ni++)
                acc[mi][ni] = __builtin_amdgcn_mfma_f32_16x16x32_f16(bf[ni], af[mi], acc[mi][ni], 0, 0, 0);
    }
#pragma unroll
    for (int mi = 0; mi < 4; mi++) {
        int row = m0 + wm + mi * 16 + lm;
#pragma unroll
        for (int ni = 0; ni < 4; ni++) {
            int col0 = n0 + wn + ni * 16 + q4 * 4;
            float bv[4] = {0.f, 0.f, 0.f, 0.f};
            if (bias) { float4 b4 = *(const float4*)(bias + col0); bv[0]=b4.x; bv[1]=b4.y; bv[2]=b4.z; bv[3]=b4.w; }
            if (Cf16) {
                h4v o;
#pragma unroll
                for (int r = 0; r < 4; r++) o[r] = (_Float16)(acc[mi][ni][r] * outscale + bv[r]);
                *(h4v*)(Cf16 + (size_t)row * ldc + col0) = o;
            } else {
                ushort4 o;
                o.x = f2bf(acc[mi][ni][0] * outscale + bv[0]);
                o.y = f2bf(acc[mi][ni][1] * outscale + bv[1]);
                o.z = f2bf(acc[mi][ni][2] * outscale + bv[2]);
                o.w = f2bf(acc[mi][ni][3] * outscale + bv[3]);
                *(ushort4*)(Cbf16 + (size_t)row * ldc + col0) = o;
            }
        }
    }
}

// ---------- ctx partials: block (bhl, slice) accumulates 256 n's into num/Ssum via atomics ----------
// kv chunk layout: [nb*1024][1024] f16, k_h at col h*64, v_h at col 512+h*64
__global__ __launch_bounds__(256) void ctx_partial(const _Float16* __restrict__ kv,
                                                   float* __restrict__ num,
                                                   float* __restrict__ Ssum, int bh0) {
    int bl = blockIdx.x;                 // local b*8+h
    int b = bl >> 3, h = bl & 7;
    int slice = blockIdx.y;              // 0..3, each 256 n's
    __shared__ __attribute__((aligned(16))) _Float16 ks[16][64];
    __shared__ __attribute__((aligned(16))) _Float16 vs[16][64];
    int t = threadIdx.x;
    int d = t >> 2, eg = t & 3;
    int lrow = t >> 4, lseg = t & 15;
    float acc[16];
#pragma unroll
    for (int j = 0; j < 16; j++) acc[j] = 0.f;
    float S = 0.f;

    int nbeg = slice * 256, nend = nbeg + 256;
    for (int n0 = nbeg; n0 < nend; n0 += 16) {
        __syncthreads();
        const _Float16* src = kv + ((size_t)b * 1024 + n0 + lrow) * 1024 + h * 64 +
                              (lseg < 8 ? lseg * 8 : 512 + (lseg - 8) * 8);
        uint4 val = *(const uint4*)src;
        if (lseg < 8) *(uint4*)(&ks[lrow][lseg * 8]) = val;
        else          *(uint4*)(&vs[lrow][(lseg - 8) * 8]) = val;
        __syncthreads();
#pragma unroll 4
        for (int nn = 0; nn < 16; nn++) {
            float ek = __expf(clampf((float)ks[nn][d], -30.f, 30.f));
            S += ek;
            union { uint4 u; _Float16 hh[8]; } v0, v1;
            v0.u = *(const uint4*)(&vs[nn][eg * 16]);
            v1.u = *(const uint4*)(&vs[nn][eg * 16 + 8]);
#pragma unroll
            for (int j = 0; j < 8; j++) acc[j] += ek * (float)v0.hh[j];
#pragma unroll
            for (int j = 0; j < 8; j++) acc[8 + j] += ek * (float)v1.hh[j];
        }
    }
    float* nd = num + (size_t)(bh0 + bl) * 4096 + d * 64 + eg * 16;
#pragma unroll
    for (int j = 0; j < 16; j++) atomicAdd(nd + j, acc[j]);
    if (eg == 0) atomicAdd(Ssum + (size_t)(bh0 + bl) * 64 + d, S);
}

// ---------- fused q-softmax + PV: attn[n][h*64+e] = sum_d (softmax_d(q)/8)[d] * (num[d][e]/S[d]) ----------
__global__ __launch_bounds__(256) void attnout_kernel(const _Float16* __restrict__ qbuf,
                                                      const float* __restrict__ num,
                                                      const float* __restrict__ Ssum,
                                                      _Float16* __restrict__ attn, int bh0) {
    int bid = blockIdx.x;
    int nc = bid & 15, h = (bid >> 4) & 7, b = bid >> 7;   // b chunk-local
    __shared__ float cs[64][64];
    __shared__ float invS[64];
    int t = threadIdx.x, wave = t >> 6, lane = t & 63;
    int bh = bh0 + b * 8 + h;
    if (t < 64) invS[t] = 1.f / Ssum[(size_t)bh * 64 + t];
    __syncthreads();
    const float4* src = (const float4*)(num + (size_t)bh * 4096);
    float4* csf = (float4*)(&cs[0][0]);
    for (int i = t; i < 1024; i += 256) {
        float4 v = src[i];
        float is = invS[i >> 4];
        v.x *= is; v.y *= is; v.z *= is; v.w *= is;
        csf[i] = v;
    }
    __syncthreads();
    for (int r = 0; r < 16; r++) {
        int n = nc * 64 + r * 4 + wave;
        size_t p = ((size_t)b * 1024 + n) * 512 + h * 64;
        float qe = __expf(clampf((float)qbuf[p + lane], -30.f, 30.f));
        float ssum = qe;
#pragma unroll
        for (int off = 1; off < 64; off <<= 1) ssum += __shfl_xor(ssum, off);
        float qn = qe / (ssum * 8.f);          // softmax / sqrt(64)
        float o = 0.f;
        for (int d = 0; d < 64; d++) o += __shfl(qn, d) * cs[d][lane];
        attn[((size_t)b * 1024 + n) * 512 + h * 64 + lane] = (_Float16)o;
    }
}

// ---------- LN2 + residual: out = LN(proj)*scale + x  (proj bf16, x/out f32) ----------
__global__ __launch_bounds__(256) void ln2_res_kernel(const unsigned short* __restrict__ proj,
                                                      const float* __restrict__ x,
                                                      const float* __restrict__ scale,
                                                      float* __restrict__ out) {
    int row = blockIdx.x * 4 + (threadIdx.x >> 6);
    int lane = threadIdx.x & 63;
    size_t off = (size_t)row * 512 + lane * 8;
    union { uint4 u; unsigned short us[8]; } pv;
    pv.u = *(const uint4*)(proj + off);
    const float4* xp = (const float4*)(x + off);
    float4 xa = xp[0], xb = xp[1];
    const float4* sp = (const float4*)(scale + lane * 8);
    float4 s0v = sp[0], s1v = sp[1];
    float xr[8] = {xa.x, xa.y, xa.z, xa.w, xb.x, xb.y, xb.z, xb.w};
    float sc[8] = {s0v.x, s0v.y, s0v.z, s0v.w, s1v.x, s1v.y, s1v.z, s1v.w};
    float f[8], s = 0.f, ss = 0.f;
#pragma unroll
    for (int j = 0; j < 8; j++) { f[j] = bf2f(pv.us[j]); s += f[j]; ss += f[j] * f[j]; }
#pragma unroll
    for (int o2 = 1; o2 < 64; o2 <<= 1) { s += __shfl_xor(s, o2); ss += __shfl_xor(ss, o2); }
    float mean = s * (1.f / 512.f);
    float var  = ss * (1.f / 512.f) - mean * mean;
    float rs   = rsqrtf(fmaxf(var, 0.f) + 1e-5f);
    float4 o0, o1;
    float* o0p = &o0.x; float* o1p = &o1.x;
#pragma unroll
    for (int j = 0; j < 4; j++) o0p[j] = (f[j] - mean) * rs * sc[j] + xr[j];
#pragma unroll
    for (int j = 0; j < 4; j++) o1p[j] = (f[4 + j] - mean) * rs * sc[4 + j] + xr[4 + j];
    float4* op = (float4*)(out + off);
    op[0] = o0; op[1] = o1;
}

// ---------- launch ----------
extern "C" void kernel_launch(void* const* d_in, const int* in_sizes, int n_in,
                              void* d_out, int out_size, void* d_ws, size_t ws_size,
                              hipStream_t stream) {
    const float* x    = (const float*)d_in[0];
    const float* ln1s = (const float*)d_in[1];
    const float* wqkv = (const float*)d_in[2];
    const float* wout = (const float*)d_in[3];
    const float* bout = (const float*)d_in[4];
    const float* ln2s = (const float*)d_in[5];
    float* out = (float*)d_out;

    char* ws = (char*)d_ws;
    // ws (~40 MB): wqkvT f16 | woutT f16 | num f32 [256][64][64] | Ssum f32 [256][64] | normed f16
    _Float16* wqkvT  = (_Float16*)(ws);                    // 1,572,864
    _Float16* woutT  = (_Float16*)(ws + 1572864);          //   524,288
    float*    num    = (float*)(ws + 2097152);             // 4,194,304
    float*    Ssum   = (float*)(ws + 6291456);             //    65,536
    _Float16* normed = (_Float16*)(ws + 6356992);          // 33,554,432
    unsigned short* proj = (unsigned short*)(ws + 6356992); // reuses dead normed slot (bf16)
    // d_out doubles as scratch: attn f16 in first half, kv/q chunk f16 in second half
    _Float16* attnF = (_Float16*)d_out;
    _Float16* kvbuf = (_Float16*)((char*)d_out + 33554432);

    const int nb = 16, nchunks = 2;

    transpose_f2h<<<dim3(48, 16), 256, 0, stream>>>(wqkv, wqkvT, 512, 1536);
    transpose_f2h<<<dim3(16, 16), 256, 0, stream>>>(wout, woutT, 512, 512);
    ln1_kernel<<<8192, 256, 0, stream>>>(x, ln1s, normed);
    hipMemsetAsync(ws + 2097152, 0, 4259840, stream);   // zero num + Ssum

    for (int c = 0; c < nchunks; c++) {
        size_t row0 = (size_t)c * nb * 1024;
        const _Float16* normed_c = normed + row0 * 512;
        int bh0 = c * nb * 8;
        // kv = normed_c . w_qkv[:, 512:1536]
        gemm128<<<dim3(8, 128), 256, 0, stream>>>(normed_c, wqkvT + 512 * 512,
                                                  kvbuf, nullptr, nullptr, 512, 1024, 1.f);
        ctx_partial<<<dim3(nb * 8, 4), 256, 0, stream>>>(kvbuf, num, Ssum, bh0);
        // q = normed_c . w_qkv[:, 0:512]  (overwrites dead kv chunk)
        gemm128<<<dim3(4, 128), 256, 0, stream>>>(normed_c, wqkvT,
                                                  kvbuf, nullptr, nullptr, 512, 512, 1.f);
        attnout_kernel<<<nb * 128, 256, 0, stream>>>(kvbuf, num, Ssum, attnF + row0 * 512, bh0);
    }

    // proj = attn . w_out^T * (1/1024) + b_out
    gemm128<<<dim3(4, 256), 256, 0, stream>>>(attnF, woutT, nullptr, proj, bout,
                                              512, 512, 1.f / 1024.f);
    ln2_res_kernel<<<8192, 256, 0, stream>>>(proj, x, ln2s, out);
}

// Round 6
// 633.327 us; speedup vs baseline: 1.3395x; 1.2736x over previous
//
#include <hip/hip_runtime.h>
#include <stdint.h>

// ---------- types / helpers ----------
typedef _Float16 h8 __attribute__((ext_vector_type(8)));
typedef _Float16 h4v __attribute__((ext_vector_type(4)));
typedef float f32x4 __attribute__((ext_vector_type(4)));

__device__ __forceinline__ float clampf(float x, float lo, float hi) {
    return fminf(fmaxf(x, lo), hi);
}
__device__ __forceinline__ unsigned short f2bf(float f) {
    unsigned int v;
    __builtin_memcpy(&v, &f, 4);
    v += 0x7FFFu + ((v >> 16) & 1u);
    return (unsigned short)(v >> 16);
}
__device__ __forceinline__ float bf2f(unsigned short u) {
    unsigned int v = ((unsigned int)u) << 16;
    float f;
    __builtin_memcpy(&f, &v, 4);
    return f;
}
// async global->LDS, 16B per lane; lds dest must be wave-uniform base (+ lane*16 implied)
__device__ __forceinline__ void gload16(const _Float16* g, _Float16* l) {
    __builtin_amdgcn_global_load_lds(
        (const __attribute__((address_space(1))) unsigned int*)g,
        (__attribute__((address_space(3))) unsigned int*)l, 16, 0, 0);
}

// ---------- transpose f32 -> f16 (out[c][r] = in[r][c]) ----------
__global__ __launch_bounds__(256) void transpose_f2h(const float* __restrict__ in,
                                                     _Float16* __restrict__ out,
                                                     int rows, int cols) {
    __shared__ _Float16 tile[32][33];
    int bx = blockIdx.x * 32, by = blockIdx.y * 32;
    int tx = threadIdx.x & 31, ty = threadIdx.x >> 5;
    for (int i = ty; i < 32; i += 8)
        tile[i][tx] = (_Float16)in[(size_t)(by + i) * cols + bx + tx];
    __syncthreads();
    for (int i = ty; i < 32; i += 8)
        out[(size_t)(bx + i) * rows + by + tx] = tile[tx][i];
}

// ---------- LN1: f32 x -> f16 normed (one wave per 512-ch row) ----------
__global__ __launch_bounds__(256) void ln1_kernel(const float* __restrict__ x,
                                                  const float* __restrict__ scale,
                                                  _Float16* __restrict__ out) {
    int row = blockIdx.x * 4 + (threadIdx.x >> 6);
    int lane = threadIdx.x & 63;
    const float4* xp = (const float4*)(x + (size_t)row * 512 + lane * 8);
    float4 a = xp[0], b = xp[1];
    const float4* sp = (const float4*)(scale + lane * 8);
    float4 s0v = sp[0], s1v = sp[1];
    float f[8] = {a.x, a.y, a.z, a.w, b.x, b.y, b.z, b.w};
    float sc[8] = {s0v.x, s0v.y, s0v.z, s0v.w, s1v.x, s1v.y, s1v.z, s1v.w};
    float s = 0.f, ss = 0.f;
#pragma unroll
    for (int j = 0; j < 8; j++) { s += f[j]; ss += f[j] * f[j]; }
#pragma unroll
    for (int off = 1; off < 64; off <<= 1) { s += __shfl_xor(s, off); ss += __shfl_xor(ss, off); }
    float mean = s * (1.f / 512.f);
    float var  = ss * (1.f / 512.f) - mean * mean;
    float rs   = rsqrtf(fmaxf(var, 0.f) + 1e-5f);
    union { uint4 u; _Float16 h[8]; } ov;
#pragma unroll
    for (int j = 0; j < 8; j++) ov.h[j] = (_Float16)((f[j] - mean) * rs * sc[j]);
    *(uint4*)(out + (size_t)row * 512 + lane * 8) = ov.u;
}

// ---------- GEMM 128x128 tile (m97-style: unpadded LDS + global_load_lds) ----------
// C[M][:] = A[M][K] * BT[N][K]^T, f16 in, fp32 acc. 4 waves 2x2, 4x4 MFMA tiles/wave.
__global__ __launch_bounds__(256) void gemm128(const _Float16* __restrict__ A,
                                               const _Float16* __restrict__ BT,
                                               _Float16* __restrict__ Cf16,
                                               unsigned short* __restrict__ Cbf16,
                                               const float* __restrict__ bias,
                                               int K, int ldc, float outscale) {
    __shared__ __attribute__((aligned(16))) _Float16 As[128 * 32];
    __shared__ __attribute__((aligned(16))) _Float16 Bs[128 * 32];
    int t = threadIdx.x, w = t >> 6, lane = t & 63;
    int lm = lane & 15, q4 = lane >> 4;
    int m0 = blockIdx.y * 128, n0 = blockIdx.x * 128;
    int wm = (w & 1) * 64, wn = (w >> 1) * 64;
    f32x4 acc[4][4];
#pragma unroll
    for (int i = 0; i < 4; i++)
#pragma unroll
        for (int j = 0; j < 4; j++) acc[i][j] = (f32x4){0.f, 0.f, 0.f, 0.f};

    int sr = t >> 2, sc = (t & 3) * 8;   // sr 0..63, sc {0,8,16,24}
    const _Float16* Ag = A + (size_t)(m0 + sr) * K + sc;
    const _Float16* Bg = BT + (size_t)(n0 + sr) * K + sc;
    _Float16* AsW = As + w * 16 * 32;    // wave-uniform LDS bases (lane*16B implied)
    _Float16* BsW = Bs + w * 16 * 32;

    for (int k0 = 0; k0 < K; k0 += 32) {
        gload16(Ag + k0, AsW);
        gload16(Ag + (size_t)64 * K + k0, AsW + 64 * 32);
        gload16(Bg + k0, BsW);
        gload16(Bg + (size_t)64 * K + k0, BsW + 64 * 32);
        __syncthreads();                 // drains vmcnt -> LDS valid
        h8 af[4], bf[4];
#pragma unroll
        for (int i = 0; i < 4; i++) af[i] = *(const h8*)(As + (wm + i * 16 + lm) * 32 + q4 * 8);
#pragma unroll
        for (int i = 0; i < 4; i++) bf[i] = *(const h8*)(Bs + (wn + i * 16 + lm) * 32 + q4 * 8);
#pragma unroll
        for (int mi = 0; mi < 4; mi++)
#pragma unroll
            for (int ni = 0; ni < 4; ni++)
                acc[mi][ni] = __builtin_amdgcn_mfma_f32_16x16x32_f16(bf[ni], af[mi], acc[mi][ni], 0, 0, 0);
        __syncthreads();                 // all reads done before next iter's loads
    }
#pragma unroll
    for (int mi = 0; mi < 4; mi++) {
        int row = m0 + wm + mi * 16 + lm;
#pragma unroll
        for (int ni = 0; ni < 4; ni++) {
            int col0 = n0 + wn + ni * 16 + q4 * 4;
            float bv[4] = {0.f, 0.f, 0.f, 0.f};
            if (bias) { float4 b4 = *(const float4*)(bias + col0); bv[0]=b4.x; bv[1]=b4.y; bv[2]=b4.z; bv[3]=b4.w; }
            if (Cf16) {
                h4v o;
#pragma unroll
                for (int r = 0; r < 4; r++) o[r] = (_Float16)(acc[mi][ni][r] * outscale + bv[r]);
                *(h4v*)(Cf16 + (size_t)row * ldc + col0) = o;
            } else {
                ushort4 o;
                o.x = f2bf(acc[mi][ni][0] * outscale + bv[0]);
                o.y = f2bf(acc[mi][ni][1] * outscale + bv[1]);
                o.z = f2bf(acc[mi][ni][2] * outscale + bv[2]);
                o.w = f2bf(acc[mi][ni][3] * outscale + bv[3]);
                *(ushort4*)(Cbf16 + (size_t)row * ldc + col0) = o;
            }
        }
    }
}

// ---------- kv transpose + exp(k) + S partials ----------
// in: kvc [8192][1024] f16 (k at col h*64+d, v at col 512+h*64+e), rows = b_local*1024 + n_local
// out: ekT[(b*8+h)*64+d][1024 n], vT[(b*8+h)*64+e][1024 n], Sbuf[bh][d] += sum ek
__global__ __launch_bounds__(256) void kv_texp(const _Float16* __restrict__ kvc,
                                               _Float16* __restrict__ ekT,
                                               _Float16* __restrict__ vT,
                                               float* __restrict__ Sbuf) {
    __shared__ _Float16 tile[64][72];
    int t = threadIdx.x;
    int n0 = blockIdx.x * 64, c0 = blockIdx.y * 64;
    int r = t >> 3, cs8 = (t & 7) * 8;
#pragma unroll
    for (int p = 0; p < 2; p++) {
        int rr = p * 32 + r;
        *(uint4*)(&tile[rr][cs8]) = *(const uint4*)(kvc + (size_t)(n0 + rr) * 1024 + c0 + cs8);
    }
    __syncthreads();
    int bl = n0 >> 10;          // batch index within chunk (tiles never straddle: 64 | 1024)
    int nl0 = n0 & 1023;
    bool isK = (c0 < 512);
#pragma unroll
    for (int p = 0; p < 2; p++) {
        int oc = p * 32 + r;
        int c = c0 + oc;
        int h = (c >> 6) & 7, de = c & 63;
        union { uint4 u; _Float16 hh[8]; } o;
        if (isK) {
            float ssum = 0.f;
#pragma unroll
            for (int j = 0; j < 8; j++) {
                float ek = __expf(clampf((float)tile[cs8 + j][oc], -30.f, 30.f));
                _Float16 e16 = (_Float16)ek;
                o.hh[j] = e16;
                ssum += (float)e16;     // sum the f16-rounded value the GEMM will use
            }
#pragma unroll
            for (int off = 1; off < 8; off <<= 1) ssum += __shfl_xor(ssum, off); // 8 lanes share oc
            *(uint4*)(ekT + ((size_t)(bl * 8 + h) * 64 + de) * 1024 + nl0 + cs8) = o.u;
            if ((t & 7) == 0) atomicAdd(&Sbuf[(bl * 8 + h) * 64 + de], ssum);
        } else {
#pragma unroll
            for (int j = 0; j < 8; j++) o.hh[j] = tile[cs8 + j][oc];
            *(uint4*)(vT + ((size_t)(bl * 8 + h) * 64 + de) * 1024 + nl0 + cs8) = o.u;
        }
    }
}

// ---------- ctx GEMM: part[ks][bh][d][e] = sum_{n in slice} ekT[bh][d][n] * vT[bh][e][n] ----------
// grid (64 bh, 4 kslice); 4 waves: wave w -> d-rows w*16..+15, all 64 e
__global__ __launch_bounds__(256) void ctx_gemm(const _Float16* __restrict__ ekT,
                                                const _Float16* __restrict__ vT,
                                                float* __restrict__ part) {
    __shared__ __attribute__((aligned(16))) _Float16 As[64 * 32];
    __shared__ __attribute__((aligned(16))) _Float16 Bs[64 * 32];
    int t = threadIdx.x, w = t >> 6, lane = t & 63;
    int lm = lane & 15, q4 = lane >> 4;
    int bhl = blockIdx.x, ks = blockIdx.y;
    int sr = t >> 2, sc = (t & 3) * 8;
    const _Float16* Ag = ekT + (size_t)bhl * 64 * 1024 + (size_t)sr * 1024 + ks * 256 + sc;
    const _Float16* Bg = vT  + (size_t)bhl * 64 * 1024 + (size_t)sr * 1024 + ks * 256 + sc;
    _Float16* AsW = As + w * 16 * 32;
    _Float16* BsW = Bs + w * 16 * 32;
    f32x4 acc[4];
#pragma unroll
    for (int i = 0; i < 4; i++) acc[i] = (f32x4){0.f, 0.f, 0.f, 0.f};

    for (int k0 = 0; k0 < 256; k0 += 32) {
        gload16(Ag + k0, AsW);
        gload16(Bg + k0, BsW);
        __syncthreads();
        h8 af = *(const h8*)(As + (w * 16 + lm) * 32 + q4 * 8);
#pragma unroll
        for (int nt = 0; nt < 4; nt++) {
            h8 bf = *(const h8*)(Bs + (nt * 16 + lm) * 32 + q4 * 8);
            acc[nt] = __builtin_amdgcn_mfma_f32_16x16x32_f16(bf, af, acc[nt], 0, 0, 0);
        }
        __syncthreads();
    }
    float* dst = part + ((size_t)ks * 64 + bhl) * 4096 + (w * 16 + lm) * 64;
#pragma unroll
    for (int nt = 0; nt < 4; nt++)
        *(f32x4*)(dst + nt * 16 + q4 * 4) = acc[nt];
}

// ---------- fused q-softmax + PV: attn[n][h*64+e] = sum_d (softmax_d(q)/8)[d] * ctx[d][e] ----------
__global__ __launch_bounds__(256) void attnout_kernel(const _Float16* __restrict__ qbuf,
                                                      const float* __restrict__ part,
                                                      const float* __restrict__ Sbuf,
                                                      _Float16* __restrict__ attn) {
    int bid = blockIdx.x;
    int nc = bid & 15, h = (bid >> 4) & 7, b = bid >> 7;   // b chunk-local
    int bhl = b * 8 + h;
    __shared__ float cs[64][64];
    __shared__ float invS[64];
    int t = threadIdx.x, wave = t >> 6, lane = t & 63;
    if (t < 64) invS[t] = 1.f / Sbuf[bhl * 64 + t];
    __syncthreads();
    const f32x4* p0 = (const f32x4*)(part + ((size_t)0 * 64 + bhl) * 4096);
    const f32x4* p1 = (const f32x4*)(part + ((size_t)1 * 64 + bhl) * 4096);
    const f32x4* p2 = (const f32x4*)(part + ((size_t)2 * 64 + bhl) * 4096);
    const f32x4* p3 = (const f32x4*)(part + ((size_t)3 * 64 + bhl) * 4096);
    f32x4* csf = (f32x4*)(&cs[0][0]);
    for (int i = t; i < 1024; i += 256) {
        f32x4 v = p0[i] + p1[i] + p2[i] + p3[i];
        v *= invS[i >> 4];
        csf[i] = v;
    }
    __syncthreads();
    for (int r = 0; r < 16; r++) {
        int n = nc * 64 + r * 4 + wave;
        size_t p = ((size_t)b * 1024 + n) * 512 + h * 64;
        float qe = __expf(clampf((float)qbuf[p + lane], -30.f, 30.f));
        float ssum = qe;
#pragma unroll
        for (int off = 1; off < 64; off <<= 1) ssum += __shfl_xor(ssum, off);
        float qn = qe / (ssum * 8.f);          // softmax / sqrt(64)
        float o = 0.f;
        for (int d = 0; d < 64; d++) o += __shfl(qn, d) * cs[d][lane];
        attn[((size_t)b * 1024 + n) * 512 + h * 64 + lane] = (_Float16)o;
    }
}

// ---------- LN2 + residual: out = LN(proj)*scale + x  (proj bf16, x/out f32) ----------
__global__ __launch_bounds__(256) void ln2_res_kernel(const unsigned short* __restrict__ proj,
                                                      const float* __restrict__ x,
                                                      const float* __restrict__ scale,
                                                      float* __restrict__ out) {
    int row = blockIdx.x * 4 + (threadIdx.x >> 6);
    int lane = threadIdx.x & 63;
    size_t off = (size_t)row * 512 + lane * 8;
    union { uint4 u; unsigned short us[8]; } pv;
    pv.u = *(const uint4*)(proj + off);
    const float4* xp = (const float4*)(x + off);
    float4 xa = xp[0], xb = xp[1];
    const float4* sp = (const float4*)(scale + lane * 8);
    float4 s0v = sp[0], s1v = sp[1];
    float xr[8] = {xa.x, xa.y, xa.z, xa.w, xb.x, xb.y, xb.z, xb.w};
    float sc[8] = {s0v.x, s0v.y, s0v.z, s0v.w, s1v.x, s1v.y, s1v.z, s1v.w};
    float f[8], s = 0.f, ss = 0.f;
#pragma unroll
    for (int j = 0; j < 8; j++) { f[j] = bf2f(pv.us[j]); s += f[j]; ss += f[j] * f[j]; }
#pragma unroll
    for (int o2 = 1; o2 < 64; o2 <<= 1) { s += __shfl_xor(s, o2); ss += __shfl_xor(ss, o2); }
    float mean = s * (1.f / 512.f);
    float var  = ss * (1.f / 512.f) - mean * mean;
    float rs   = rsqrtf(fmaxf(var, 0.f) + 1e-5f);
    float4 o0, o1;
    float* o0p = &o0.x; float* o1p = &o1.x;
#pragma unroll
    for (int j = 0; j < 4; j++) o0p[j] = (f[j] - mean) * rs * sc[j] + xr[j];
#pragma unroll
    for (int j = 0; j < 4; j++) o1p[j] = (f[4 + j] - mean) * rs * sc[4 + j] + xr[4 + j];
    float4* op = (float4*)(out + off);
    op[0] = o0; op[1] = o1;
}

// ---------- launch ----------
extern "C" void kernel_launch(void* const* d_in, const int* in_sizes, int n_in,
                              void* d_out, int out_size, void* d_ws, size_t ws_size,
                              hipStream_t stream) {
    const float* x    = (const float*)d_in[0];
    const float* ln1s = (const float*)d_in[1];
    const float* wqkv = (const float*)d_in[2];
    const float* wout = (const float*)d_in[3];
    const float* bout = (const float*)d_in[4];
    const float* ln2s = (const float*)d_in[5];
    float* out = (float*)d_out;

    char* ws = (char*)d_ws;
    // ws (~38 MB): wqkvT | woutT | ctx_part f32 [4][64][4096] | Sbuf f32 [64][64] | normed f16
    _Float16* wqkvT  = (_Float16*)(ws);                     // 1,572,864
    _Float16* woutT  = (_Float16*)(ws + 1572864);           //   524,288
    float*    part   = (float*)(ws + 2097152);              // 4,194,304
    float*    Sbuf   = (float*)(ws + 6291456);              //    16,384
    _Float16* normed = (_Float16*)(ws + 6356992);           // 33,554,432
    unsigned short* proj = (unsigned short*)(ws + 6356992); // reuses dead normed slot (bf16)
    // d_out (64 MiB) doubles as scratch, all dead before ln2 writes:
    _Float16* attnF = (_Float16*)d_out;                          // [32768][512] f16 : 32 MiB
    _Float16* kvbuf = (_Float16*)((char*)d_out + 33554432);      // chunk [8192][1024] f16 : 16 MiB (later qbuf)
    _Float16* ekT   = (_Float16*)((char*)d_out + 50331648);      // chunk [64*64][1024] f16 : 8 MiB
    _Float16* vT    = (_Float16*)((char*)d_out + 58720256);      // chunk [64*64][1024] f16 : 8 MiB

    const int nb = 8, nchunks = 4;

    transpose_f2h<<<dim3(48, 16), 256, 0, stream>>>(wqkv, wqkvT, 512, 1536);
    transpose_f2h<<<dim3(16, 16), 256, 0, stream>>>(wout, woutT, 512, 512);
    ln1_kernel<<<8192, 256, 0, stream>>>(x, ln1s, normed);

    for (int c = 0; c < nchunks; c++) {
        size_t row0 = (size_t)c * nb * 1024;
        const _Float16* normed_c = normed + row0 * 512;
        hipMemsetAsync(Sbuf, 0, 16384, stream);
        // kv = normed_c . w_qkv[:, 512:1536]   [8192 x 1024]
        gemm128<<<dim3(8, 64), 256, 0, stream>>>(normed_c, wqkvT + 512 * 512,
                                                 kvbuf, nullptr, nullptr, 512, 1024, 1.f);
        kv_texp<<<dim3(128, 16), 256, 0, stream>>>(kvbuf, ekT, vT, Sbuf);
        ctx_gemm<<<dim3(64, 4), 256, 0, stream>>>(ekT, vT, part);
        // q = normed_c . w_qkv[:, 0:512]  (kvbuf now dead -> qbuf)
        gemm128<<<dim3(4, 64), 256, 0, stream>>>(normed_c, wqkvT,
                                                 kvbuf, nullptr, nullptr, 512, 512, 1.f);
        attnout_kernel<<<nb * 128, 256, 0, stream>>>(kvbuf, part, Sbuf, attnF + row0 * 512);
    }

    // proj = attn . w_out^T * (1/1024) + b_out
    gemm128<<<dim3(4, 256), 256, 0, stream>>>(attnF, woutT, nullptr, proj, bout,
                                              512, 512, 1.f / 1024.f);
    ln2_res_kernel<<<8192, 256, 0, stream>>>(proj, x, ln2s, out);
}